// Round 1
// baseline (1284.032 us; speedup 1.0000x reference)
//
#include <hip/hip_runtime.h>

// B=64, S=512, I=256, O=256 fp32 LSTM.
// out = [h_seq (64*512*256)] [hT (64*256)] [cT (64*256)]
//
// Phase A: xg = x @ Wx^T + bx + bh  (fp32 LDS-tiled GEMM, unchanged)
// Phase B: one block per batch (64 blocks, 512 threads). Wh fp16:
//   k in [0,192) in VGPRs (96 half2 per row x 2 rows = 192 VGPRs),
//   k in [192,256) in LDS (128 KB). h(t) is wave-uniform -> distributed via
//   ONE distinct-address ds_read_b128 + v_readlane into SGPRs; v_dot2_f32_f16
//   consumes the SGPR operand directly. This removes the 32 broadcast
//   ds_read_b128/thread/step that made the old kernel LDS-pipe-bound
//   (384 LDS insts/step * 12cy = 4608cy/step == measured 4587cy/step).

#define SS 512

typedef _Float16 h2 __attribute__((ext_vector_type(2)));

__device__ __forceinline__ h2 bch(unsigned u) { return __builtin_bit_cast(h2, u); }

__device__ __forceinline__ unsigned rl(unsigned v, int lane) {
  return (unsigned)__builtin_amdgcn_readlane((int)v, lane);
}

#if __has_builtin(__builtin_amdgcn_fdot2)
__device__ __forceinline__ float dot2f(h2 a, h2 b, float c) {
  return __builtin_amdgcn_fdot2(a, b, c, false);
}
#else
__device__ __forceinline__ float dot2f(h2 a, h2 b, float c) {
  return c + (float)a[0] * (float)b[0] + (float)a[1] * (float)b[1];
}
#endif

__device__ __forceinline__ float sigm(float x) { return 1.f / (1.f + __expf(-x)); }
__device__ __forceinline__ float tanh_f(float x) {
  float e = __expf(-2.f * fabsf(x));      // e in (0,1], no overflow
  float r = (1.f - e) / (1.f + e);
  return copysignf(r, x);
}

// ---------------------------------------------------------------- Phase A
__global__ __launch_bounds__(256) void xg_gemm(
    const float* __restrict__ X, const float* __restrict__ W,
    const float* __restrict__ bx, const float* __restrict__ bh,
    float* __restrict__ out)
{
  __shared__ float As[64][68];
  __shared__ float Bs[64][68];
  const int bm = blockIdx.x >> 4;
  const int bn = blockIdx.x & 15;
  const int tid = threadIdx.x;
  const int tn = tid & 15, tm = tid >> 4;
  const int row0 = bm * 64, col0 = bn * 64;
  float acc[4][4] = {};

  for (int k0 = 0; k0 < 256; k0 += 64) {
#pragma unroll
    for (int i = 0; i < 4; i++) {
      const int m = (tid >> 4) + i * 16;
      const int k = (tid & 15) * 4;
      float4 av = *(const float4*)&X[(size_t)(row0 + m) * 256 + k0 + k];
      *(float4*)&As[m][k] = av;
      float4 wv = *(const float4*)&W[(size_t)(col0 + m) * 256 + k0 + k];
      Bs[k + 0][m] = wv.x; Bs[k + 1][m] = wv.y;
      Bs[k + 2][m] = wv.z; Bs[k + 3][m] = wv.w;
    }
    __syncthreads();
#pragma unroll 8
    for (int kk = 0; kk < 64; kk++) {
      const float a0 = As[tm * 4 + 0][kk];
      const float a1 = As[tm * 4 + 1][kk];
      const float a2 = As[tm * 4 + 2][kk];
      const float a3 = As[tm * 4 + 3][kk];
      const float4 bv = *(const float4*)&Bs[kk][tn * 4];
      acc[0][0] = fmaf(a0, bv.x, acc[0][0]); acc[0][1] = fmaf(a0, bv.y, acc[0][1]);
      acc[0][2] = fmaf(a0, bv.z, acc[0][2]); acc[0][3] = fmaf(a0, bv.w, acc[0][3]);
      acc[1][0] = fmaf(a1, bv.x, acc[1][0]); acc[1][1] = fmaf(a1, bv.y, acc[1][1]);
      acc[1][2] = fmaf(a1, bv.z, acc[1][2]); acc[1][3] = fmaf(a1, bv.w, acc[1][3]);
      acc[2][0] = fmaf(a2, bv.x, acc[2][0]); acc[2][1] = fmaf(a2, bv.y, acc[2][1]);
      acc[2][2] = fmaf(a2, bv.z, acc[2][2]); acc[2][3] = fmaf(a2, bv.w, acc[2][3]);
      acc[3][0] = fmaf(a3, bv.x, acc[3][0]); acc[3][1] = fmaf(a3, bv.y, acc[3][1]);
      acc[3][2] = fmaf(a3, bv.z, acc[3][2]); acc[3][3] = fmaf(a3, bv.w, acc[3][3]);
    }
    __syncthreads();
  }

  float bias[4];
#pragma unroll
  for (int j = 0; j < 4; j++) {
    const int col = col0 + tn * 4 + j;
    bias[j] = bx[col] + bh[col];
  }
#pragma unroll
  for (int i = 0; i < 4; i++) {
    float4 o4;
    o4.x = acc[i][0] + bias[0]; o4.y = acc[i][1] + bias[1];
    o4.z = acc[i][2] + bias[2]; o4.w = acc[i][3] + bias[3];
    *(float4*)&out[(size_t)(row0 + tm * 4 + i) * 1024 + col0 + tn * 4] = o4;
  }
}

// ---------------------------------------------------------------- Phase B
// Thread tid owns gate rows p0=tid (f if tid<256 else i) and p1=tid+512
// (g if tid<256 else o). k in [0,192) from VGPR fp16 weights; k in [192,256)
// from LDS fp16 weights. h comes in via SGPRs:
//   lane l (l<32) holds h dwords [4l,4l+4) from one ds_read_b128;
//   v_readlane distributes dword d (k=2d,2d+1) to all lanes as an SGPR.
__global__ __launch_bounds__(512, 1) void lstm_scan3(
    const float* __restrict__ xg,   // [64][512][1024]
    const float* __restrict__ Wh,   // [1024][256]
    const float* __restrict__ h0,   // [64][256]
    const float* __restrict__ c0,   // [64][256]
    float* __restrict__ out)
{
  // wl layout: [o(2)][chunk(8)][tid(512)][8 halves] -> contiguous 16B per lane
  __shared__ __align__(16) _Float16 wl[2 * 8 * 512 * 8];   // 128 KB
  __shared__ __align__(16) _Float16 h_sh[256];
  __shared__ float io_i[256];
  __shared__ float io_o[256];

  const int tid = threadIdx.x;
  const int b = blockIdx.x;

  const float* r0 = Wh + (size_t)tid * 256;
  const float* r1 = Wh + (size_t)(tid + 512) * 256;

  // ---- persistent register weights: k in [0,192) as 96 half2 per output row
  h2 w0[96], w1[96];
#pragma unroll
  for (int j = 0; j < 96; ++j) {
    float2 a = *(const float2*)&r0[2 * j];
    float2 c = *(const float2*)&r1[2 * j];
    h2 wa; wa[0] = (_Float16)a.x; wa[1] = (_Float16)a.y; w0[j] = wa;
    h2 wc; wc[0] = (_Float16)c.x; wc[1] = (_Float16)c.y; w1[j] = wc;
  }
  // ---- LDS weights: k in [192,256)
#pragma unroll
  for (int c = 0; c < 8; ++c) {
#pragma unroll
    for (int e = 0; e < 8; ++e) {
      wl[((size_t)(c)*512 + tid) * 8 + e]     = (_Float16)r0[192 + c * 8 + e];
      wl[((size_t)(8 + c)*512 + tid) * 8 + e] = (_Float16)r1[192 + c * 8 + e];
    }
  }
  // ---- initial state
  if (tid < 256) h_sh[tid] = (_Float16)h0[(size_t)b * 256 + tid];
  float cr = (tid < 256) ? c0[(size_t)b * 256 + tid] : 0.f;
  __syncthreads();

  const float* xr = xg + (size_t)b * SS * 1024;
  float* hs = out + (size_t)b * SS * 256;

  for (int t = 0; t < SS; ++t) {
    const float xg0 = xr[(size_t)t * 1024 + tid];
    const float xg1 = xr[(size_t)t * 1024 + tid + 512];

    // ONE distinct-address LDS read of h: lanes 0..31 cover all 256 halves
    // (lanes 32..63 alias lanes 0..31 -> 2-way same-address, free)
    const uint4 hv = *(const uint4*)&h_sh[(tid & 31) * 8];

    float A0 = 0.f, B0 = 0.f, A1 = 0.f, B1 = 0.f;

    // chunks 0..2: k in [0,192), weights in VGPRs, h via readlane SGPRs.
    // lane group ln holds h dwords [4*ln, 4*ln+4) == w index j = 4*ln..4*ln+3.
#pragma unroll
    for (int q = 0; q < 3; ++q) {
#pragma unroll
      for (int g = 0; g < 8; ++g) {
        const int ln = q * 8 + g;
        const unsigned hu0 = rl(hv.x, ln);
        const unsigned hu1 = rl(hv.y, ln);
        const unsigned hu2 = rl(hv.z, ln);
        const unsigned hu3 = rl(hv.w, ln);
        const int j = ln * 4;
        A0 = dot2f(w0[j + 0], bch(hu0), A0); A1 = dot2f(w1[j + 0], bch(hu0), A1);
        B0 = dot2f(w0[j + 1], bch(hu1), B0); B1 = dot2f(w1[j + 1], bch(hu1), B1);
        A0 = dot2f(w0[j + 2], bch(hu2), A0); A1 = dot2f(w1[j + 2], bch(hu2), A1);
        B0 = dot2f(w0[j + 3], bch(hu3), B0); B1 = dot2f(w1[j + 3], bch(hu3), B1);
      }
    }
    // chunk 3: k in [192,256), weights from LDS, h via readlane SGPRs.
    // wa covers k=[192+8c, 192+8c+8) == h dwords [96+4c, 96+4c+4) == lane 24+c.
#pragma unroll
    for (int c = 0; c < 8; ++c) {
      const uint4 wa = *(const uint4*)&wl[((size_t)(c)*512 + tid) * 8];
      const uint4 wb = *(const uint4*)&wl[((size_t)(8 + c)*512 + tid) * 8];
      const int ln = 24 + c;
      const unsigned hu0 = rl(hv.x, ln);
      const unsigned hu1 = rl(hv.y, ln);
      const unsigned hu2 = rl(hv.z, ln);
      const unsigned hu3 = rl(hv.w, ln);
      A0 = dot2f(bch(wa.x), bch(hu0), A0); A1 = dot2f(bch(wb.x), bch(hu0), A1);
      B0 = dot2f(bch(wa.y), bch(hu1), B0); B1 = dot2f(bch(wb.y), bch(hu1), B1);
      A0 = dot2f(bch(wa.z), bch(hu2), A0); A1 = dot2f(bch(wb.z), bch(hu2), A1);
      B0 = dot2f(bch(wa.w), bch(hu3), B0); B1 = dot2f(bch(wb.w), bch(hu3), B1);
    }
    const float y0 = A0 + B0 + xg0;
    const float y1 = A1 + B1 + xg1;

    float u0 = 0.f, u1 = 0.f;
    if (tid < 256) {            // rows: f=tid, g=tid+512
      u0 = sigm(y0);
      u1 = tanh_f(y1);
    } else {                    // rows: i=tid-256+256, o=tid-256+768
      io_i[tid - 256] = sigm(y0);
      io_o[tid - 256] = sigm(y1);
    }
    __syncthreads();            // io visible; all dots done reading h_sh

    if (tid < 256) {
      cr = cr * u0 + io_i[tid] * u1;
      const float h = io_o[tid] * tanh_f(cr);
      hs[(size_t)t * 256 + tid] = h;
      h_sh[tid] = (_Float16)h;
      if (t == SS - 1) {
        out[8388608 + (size_t)b * 256 + tid] = h;            // hT
        out[8404992 + (size_t)b * 256 + tid] = cr;           // cT
      }
    }
    __syncthreads();            // h_sh ready for next step
  }
}

// ---------------------------------------------------------------- launch
extern "C" void kernel_launch(void* const* d_in, const int* in_sizes, int n_in,
                              void* d_out, int out_size, void* d_ws, size_t ws_size,
                              hipStream_t stream) {
  const float* x  = (const float*)d_in[0];
  const float* h0 = (const float*)d_in[1];
  const float* c0 = (const float*)d_in[2];
  const float* Wh = (const float*)d_in[3];
  const float* bh = (const float*)d_in[4];
  const float* Wx = (const float*)d_in[5];
  const float* bx = (const float*)d_in[6];
  float* out = (float*)d_out;

  float* xg = (float*)d_ws;   // 32768*1024 floats = 128 MB

  xg_gemm<<<dim3(8192), dim3(256), 0, stream>>>(x, Wx, bx, bh, xg);
  lstm_scan3<<<dim3(64), dim3(512), 0, stream>>>(xg, Wh, h0, c0, out);
}